// Round 1
// baseline (884.437 us; speedup 1.0000x reference)
//
#include <hip/hip_runtime.h>
#include <hip/hip_bf16.h>

// ---------------------------------------------------------------------------
// BYOGPT forward: embed+PE -> 4x[QKV proj, flash-attn, LN, lin, LN] -> unembed
// B=2 S=1024 D=768 H=12 Dh=64 V=50257. bf16 MFMA GEMMs, fp32 residual/LN.
// ---------------------------------------------------------------------------

#define VOCAB 50257
#define DM 768
#define NL 4
#define NH 12
#define DH 64
#define SEQ 1024
#define BATCH 2
#define ROWS (BATCH * SEQ)   // 2048

typedef __attribute__((ext_vector_type(8))) short short8;
typedef __attribute__((ext_vector_type(4))) float f32x4;

__device__ __forceinline__ unsigned short f2bf(float f) {
    union { float f; unsigned u; } v; v.f = f;
    unsigned r = v.u + 0x7FFFu + ((v.u >> 16) & 1u);   // RNE
    return (unsigned short)(r >> 16);
}

// ---------------- fp32 -> bf16 bulk convert (weights) ----------------------
__global__ __launch_bounds__(256) void cvt_kernel(const float* __restrict__ in,
                                                  unsigned short* __restrict__ out,
                                                  int n4) {
    int i = blockIdx.x * 256 + threadIdx.x;
    if (i < n4) {
        float4 v = ((const float4*)in)[i];
        ushort4 o;
        o.x = f2bf(v.x); o.y = f2bf(v.y); o.z = f2bf(v.z); o.w = f2bf(v.w);
        ((ushort4*)out)[i] = o;
    }
}

// ---------------- embedding + positional encoding --------------------------
__global__ __launch_bounds__(256) void embed_kernel(const int* __restrict__ tok,
                                                    const float* __restrict__ emb,
                                                    const float* __restrict__ pe,
                                                    float* __restrict__ xf,
                                                    unsigned short* __restrict__ xb) {
    int row = blockIdx.x;                 // 0..2047
    int t = tok[row];
    int s = row & (SEQ - 1);
    #pragma unroll
    for (int j = 0; j < 3; ++j) {
        int c = threadIdx.x + j * 256;
        float v = emb[(size_t)t * DM + c] + pe[(size_t)s * DM + c];
        xf[(size_t)row * DM + c] = v;
        xb[(size_t)row * DM + c] = f2bf(v);
    }
}

// ---------------- residual + LayerNorm (writes fp32 + bf16) ----------------
__device__ __forceinline__ float block_sum(float x, float* red) {
    #pragma unroll
    for (int off = 32; off > 0; off >>= 1) x += __shfl_down(x, off);
    int w = threadIdx.x >> 6;
    if ((threadIdx.x & 63) == 0) red[w] = x;
    __syncthreads();
    float t = (red[0] + red[1]) + (red[2] + red[3]);
    __syncthreads();
    return t;
}

__global__ __launch_bounds__(256) void ln_kernel(const float* __restrict__ A,
                                                 const float* __restrict__ Bi,
                                                 const float* __restrict__ sc,
                                                 const float* __restrict__ bi,
                                                 float* __restrict__ xf,
                                                 unsigned short* __restrict__ xb) {
    __shared__ float red[4];
    int row = blockIdx.x, tid = threadIdx.x;
    const float* ap = A + (size_t)row * DM;
    const float* bp = Bi + (size_t)row * DM;
    float v[3], sum = 0.f;
    #pragma unroll
    for (int j = 0; j < 3; ++j) { v[j] = ap[tid + j * 256] + bp[tid + j * 256]; sum += v[j]; }
    sum = block_sum(sum, red);
    float mean = sum * (1.f / DM);
    float vs = 0.f;
    #pragma unroll
    for (int j = 0; j < 3; ++j) { float d = v[j] - mean; vs += d * d; }
    vs = block_sum(vs, red);
    float rstd = rsqrtf(vs * (1.f / DM) + 1e-5f);
    #pragma unroll
    for (int j = 0; j < 3; ++j) {
        int c = tid + j * 256;
        float o = (v[j] - mean) * rstd * sc[c] + bi[c];
        xf[(size_t)row * DM + c] = o;
        xb[(size_t)row * DM + c] = f2bf(o);
    }
}

// ---------------- generic bf16 GEMM: C[M,N] = A[M,K] * B[N,K]^T + bias -----
// 64x64 tile / block, 4 waves each 32x32, XOR-swizzled LDS, 16x16x32 MFMA.
template <int OUT_BF16>
__global__ __launch_bounds__(256) void gemm_bt(const unsigned short* __restrict__ A, int lda,
                                               const unsigned short* __restrict__ B, int ldb,
                                               const float* __restrict__ bias,
                                               void* __restrict__ C, int ldc,
                                               int M, int N, int K) {
    __shared__ __align__(16) unsigned short As[64 * 64];
    __shared__ __align__(16) unsigned short Bs[64 * 64];
    const int tid = threadIdx.x;
    const int m0 = blockIdx.x * 64;
    const int n0 = blockIdx.y * 64;
    const int lane = tid & 63, wid = tid >> 6;
    const int wm = wid >> 1, wn = wid & 1;    // wave -> 32x32 sub-tile
    const int lr = lane & 15, lq = lane >> 4;
    const int srow = tid >> 3;                // staging row 0..31
    const int scol = (tid & 7) * 8;           // staging col (8 bf16 = 16B)
    f32x4 acc[2][2] = {};

    for (int k0 = 0; k0 < K; k0 += 64) {
        #pragma unroll
        for (int r = 0; r < 2; ++r) {
            int row = r * 32 + srow;
            {   // A tile
                const unsigned short* src = A + (size_t)(m0 + row) * lda + k0 + scol;
                short8 v = *reinterpret_cast<const short8*>(src);
                *reinterpret_cast<short8*>(&As[(row * 64 + scol) ^ ((row & 7) << 3)]) = v;
            }
            {   // B tile (clamp n for the ragged vocab edge)
                int brow = n0 + row; if (brow >= N) brow = N - 1;
                const unsigned short* src = B + (size_t)brow * ldb + k0 + scol;
                short8 v = *reinterpret_cast<const short8*>(src);
                *reinterpret_cast<short8*>(&Bs[(row * 64 + scol) ^ ((row & 7) << 3)]) = v;
            }
        }
        __syncthreads();
        #pragma unroll
        for (int kk = 0; kk < 2; ++kk) {
            short8 a[2], b[2];
            int kc = kk * 32 + lq * 8;
            #pragma unroll
            for (int i = 0; i < 2; ++i) {
                int ar = wm * 32 + i * 16 + lr;
                a[i] = *reinterpret_cast<const short8*>(&As[(ar * 64 + kc) ^ ((ar & 7) << 3)]);
                int br = wn * 32 + i * 16 + lr;
                b[i] = *reinterpret_cast<const short8*>(&Bs[(br * 64 + kc) ^ ((br & 7) << 3)]);
            }
            #pragma unroll
            for (int i = 0; i < 2; ++i)
                #pragma unroll
                for (int j = 0; j < 2; ++j)
                    acc[i][j] = __builtin_amdgcn_mfma_f32_16x16x32_bf16(a[i], b[j], acc[i][j], 0, 0, 0);
        }
        __syncthreads();
    }
    // epilogue: C/D layout col=lane&15, row=(lane>>4)*4+reg  [m89-verified]
    #pragma unroll
    for (int i = 0; i < 2; ++i) {
        int row = m0 + wm * 32 + i * 16 + lq * 4;
        #pragma unroll
        for (int j = 0; j < 2; ++j) {
            int col = n0 + wn * 32 + j * 16 + lr;
            if (col < N) {
                float bv = bias[col];
                #pragma unroll
                for (int r = 0; r < 4; ++r) {
                    float v = acc[i][j][r] + bv;
                    if (OUT_BF16) ((unsigned short*)C)[(size_t)(row + r) * ldc + col] = f2bf(v);
                    else          ((float*)C)[(size_t)(row + r) * ldc + col] = v;
                }
            }
        }
    }
}

// ---------------- flash attention (causal), bf16 MFMA ----------------------
// grid (S/64, B*H); 4 waves, each owns 16 q-rows. KV tiles of 64.
__global__ __launch_bounds__(256) void attn_kernel(const unsigned short* __restrict__ Q,
                                                   const unsigned short* __restrict__ K,
                                                   const unsigned short* __restrict__ V,
                                                   float* __restrict__ O) {
    __shared__ __align__(16) unsigned short Ks[64 * 64];
    __shared__ __align__(16) unsigned short Vs[64 * 64];     // transposed [d][kv]
    __shared__ __align__(16) unsigned short Ps[4][16 * 64];  // per-wave P tile
    const int qb = blockIdx.x;
    const int bh = blockIdx.y;
    const int b = bh / NH, h = bh % NH;
    const int tid = threadIdx.x, lane = tid & 63, w = tid >> 6;
    const int lr = lane & 15, lq = lane >> 4;
    const int wq0 = qb * 64 + w * 16;
    const size_t base = (size_t)b * SEQ * DM + h * DH;

    short8 qf[2];
    {
        const unsigned short* qp = Q + base + (size_t)(wq0 + lr) * DM + lq * 8;
        qf[0] = *reinterpret_cast<const short8*>(qp);
        qf[1] = *reinterpret_cast<const short8*>(qp + 32);
    }
    f32x4 o_acc[4] = {};
    float mrow[4], lrow[4];
    #pragma unroll
    for (int r = 0; r < 4; ++r) { mrow[r] = -1e30f; lrow[r] = 0.f; }

    const int srow = tid >> 3, scol = (tid & 7) * 8;
    for (int t = 0; t <= qb; ++t) {
        const int kv0 = t * 64;
        #pragma unroll
        for (int rr = 0; rr < 2; ++rr) {
            int row = rr * 32 + srow;
            {
                const unsigned short* kp = K + base + (size_t)(kv0 + row) * DM + scol;
                short8 v = *reinterpret_cast<const short8*>(kp);
                *reinterpret_cast<short8*>(&Ks[(row * 64 + scol) ^ ((row & 7) << 3)]) = v;
            }
            {
                const unsigned short* vp = V + base + (size_t)(kv0 + row) * DM + scol;
                short8 v = *reinterpret_cast<const short8*>(vp);
                #pragma unroll
                for (int j = 0; j < 8; ++j) {   // transpose into Vs[d][kv]
                    int d = scol + j;
                    Vs[(d * 64 + row) ^ ((d & 7) << 3)] = (unsigned short)v[j];
                }
            }
        }
        __syncthreads();
        if (kv0 <= wq0 + 15) {
            // scores S = Q * Ktile^T (scaled)
            f32x4 s[4];
            #pragma unroll
            for (int n = 0; n < 4; ++n) {
                int br = n * 16 + lr;
                short8 b0 = *reinterpret_cast<const short8*>(&Ks[(br * 64 + lq * 8) ^ ((br & 7) << 3)]);
                short8 b1 = *reinterpret_cast<const short8*>(&Ks[(br * 64 + 32 + lq * 8) ^ ((br & 7) << 3)]);
                f32x4 z = {};
                z = __builtin_amdgcn_mfma_f32_16x16x32_bf16(qf[0], b0, z, 0, 0, 0);
                z = __builtin_amdgcn_mfma_f32_16x16x32_bf16(qf[1], b1, z, 0, 0, 0);
                s[n] = z;
            }
            const bool diag = (t == qb);
            #pragma unroll
            for (int n = 0; n < 4; ++n)
                #pragma unroll
                for (int r = 0; r < 4; ++r) {
                    float v = s[n][r] * 0.125f;   // 1/sqrt(64)
                    if (diag) {
                        int rg = wq0 + lq * 4 + r;
                        int cg = kv0 + n * 16 + lr;
                        if (cg > rg) v = -1e30f;
                    }
                    s[n][r] = v;
                }
            float f[4];
            #pragma unroll
            for (int r = 0; r < 4; ++r) {
                float mx = fmaxf(fmaxf(s[0][r], s[1][r]), fmaxf(s[2][r], s[3][r]));
                #pragma unroll
                for (int off = 1; off < 16; off <<= 1) mx = fmaxf(mx, __shfl_xor(mx, off));
                float mn = fmaxf(mrow[r], mx);
                f[r] = exp2f((mrow[r] - mn) * 1.44269504f);
                mrow[r] = mn;
            }
            #pragma unroll
            for (int n = 0; n < 4; ++n)
                #pragma unroll
                for (int r = 0; r < 4; ++r)
                    s[n][r] = exp2f((s[n][r] - mrow[r]) * 1.44269504f);
            #pragma unroll
            for (int r = 0; r < 4; ++r) {
                float ls = ((s[0][r] + s[1][r]) + (s[2][r] + s[3][r]));
                #pragma unroll
                for (int off = 1; off < 16; off <<= 1) ls += __shfl_xor(ls, off);
                lrow[r] = lrow[r] * f[r] + ls;
            }
            // write P (bf16) to per-wave LDS region
            #pragma unroll
            for (int n = 0; n < 4; ++n)
                #pragma unroll
                for (int r = 0; r < 4; ++r) {
                    int pr = lq * 4 + r, pc = n * 16 + lr;
                    Ps[w][(pr * 64 + pc) ^ ((pr & 7) << 3)] = f2bf(s[n][r]);
                }
            // rescale O, then O += P * Vtile
            #pragma unroll
            for (int n = 0; n < 4; ++n)
                #pragma unroll
                for (int r = 0; r < 4; ++r) o_acc[n][r] *= f[r];
            #pragma unroll
            for (int kk = 0; kk < 2; ++kk) {
                short8 pa = *reinterpret_cast<const short8*>(
                    &Ps[w][(lr * 64 + kk * 32 + lq * 8) ^ ((lr & 7) << 3)]);
                #pragma unroll
                for (int n = 0; n < 4; ++n) {
                    int vr = n * 16 + lr;
                    short8 bv = *reinterpret_cast<const short8*>(
                        &Vs[(vr * 64 + kk * 32 + lq * 8) ^ ((vr & 7) << 3)]);
                    o_acc[n] = __builtin_amdgcn_mfma_f32_16x16x32_bf16(pa, bv, o_acc[n], 0, 0, 0);
                }
            }
        }
        __syncthreads();
    }
    // normalize + store to attn buffer [2048, 768] at head offset
    #pragma unroll
    for (int r = 0; r < 4; ++r) {
        float inv = 1.f / lrow[r];
        int row = wq0 + lq * 4 + r;
        #pragma unroll
        for (int n = 0; n < 4; ++n)
            O[base + (size_t)row * DM + n * 16 + lr] = o_acc[n][r] * inv;
    }
}

// ---------------------------------------------------------------------------
extern "C" void kernel_launch(void* const* d_in, const int* in_sizes, int n_in,
                              void* d_out, int out_size, void* d_ws, size_t ws_size,
                              hipStream_t stream) {
    const int*   tokens   = (const int*)d_in[0];
    const float* embed    = (const float*)d_in[1];
    const float* pe       = (const float*)d_in[2];
    const float* wq_w     = (const float*)d_in[3];
    const float* wq_b     = (const float*)d_in[4];
    const float* wk_w     = (const float*)d_in[5];
    const float* wk_b     = (const float*)d_in[6];
    const float* wv_w     = (const float*)d_in[7];
    const float* wv_b     = (const float*)d_in[8];
    const float* lin_w    = (const float*)d_in[9];
    const float* lin_b    = (const float*)d_in[10];
    const float* n1_s     = (const float*)d_in[11];
    const float* n1_b     = (const float*)d_in[12];
    const float* n2_s     = (const float*)d_in[13];
    const float* n2_b     = (const float*)d_in[14];
    const float* unemb_w  = (const float*)d_in[15];
    const float* unemb_b  = (const float*)d_in[16];

    char* ws = (char*)d_ws;
    size_t off = 0;
    auto carve = [&](size_t bytes) { char* p = ws + off; off += (bytes + 255) & ~(size_t)255; return p; };
    float*          xf    = (float*)carve((size_t)ROWS * DM * 4);
    float*          attn  = (float*)carve((size_t)ROWS * DM * 4);
    float*          yb    = (float*)carve((size_t)ROWS * DM * 4);
    unsigned short* xb    = (unsigned short*)carve((size_t)ROWS * DM * 2);
    unsigned short* qb_   = (unsigned short*)carve((size_t)ROWS * DM * 2);
    unsigned short* kb_   = (unsigned short*)carve((size_t)ROWS * DM * 2);
    unsigned short* vb_   = (unsigned short*)carve((size_t)ROWS * DM * 2);
    unsigned short* wq_h  = (unsigned short*)carve((size_t)NL * DM * DM * 2);
    unsigned short* wk_h  = (unsigned short*)carve((size_t)NL * DM * DM * 2);
    unsigned short* wv_h  = (unsigned short*)carve((size_t)NL * DM * DM * 2);
    unsigned short* lin_h = (unsigned short*)carve((size_t)NL * DM * DM * 2);
    unsigned short* ue_h  = (unsigned short*)carve((size_t)VOCAB * DM * 2);

    // weight converts (fp32 -> bf16)
    {
        int nw4 = NL * DM * DM / 4;
        cvt_kernel<<<(nw4 + 255) / 256, 256, 0, stream>>>(wq_w, wq_h, nw4);
        cvt_kernel<<<(nw4 + 255) / 256, 256, 0, stream>>>(wk_w, wk_h, nw4);
        cvt_kernel<<<(nw4 + 255) / 256, 256, 0, stream>>>(wv_w, wv_h, nw4);
        cvt_kernel<<<(nw4 + 255) / 256, 256, 0, stream>>>(lin_w, lin_h, nw4);
        int nu4 = VOCAB * DM / 4;
        cvt_kernel<<<(nu4 + 255) / 256, 256, 0, stream>>>(unemb_w, ue_h, nu4);
    }
    embed_kernel<<<ROWS, 256, 0, stream>>>(tokens, embed, pe, xf, xb);

    for (int l = 0; l < NL; ++l) {
        const size_t wo = (size_t)l * DM * DM;
        gemm_bt<1><<<dim3(ROWS / 64, DM / 64), 256, 0, stream>>>(
            xb, DM, wq_h + wo, DM, wq_b + l * DM, qb_, DM, ROWS, DM, DM);
        gemm_bt<1><<<dim3(ROWS / 64, DM / 64), 256, 0, stream>>>(
            xb, DM, wk_h + wo, DM, wk_b + l * DM, kb_, DM, ROWS, DM, DM);
        gemm_bt<1><<<dim3(ROWS / 64, DM / 64), 256, 0, stream>>>(
            xb, DM, wv_h + wo, DM, wv_b + l * DM, vb_, DM, ROWS, DM, DM);
        attn_kernel<<<dim3(SEQ / 64, BATCH * NH), 256, 0, stream>>>(qb_, kb_, vb_, attn);
        ln_kernel<<<ROWS, 256, 0, stream>>>(xf, attn, n1_s + l * DM, n1_b + l * DM, xf, xb);
        gemm_bt<0><<<dim3(ROWS / 64, DM / 64), 256, 0, stream>>>(
            xb, DM, lin_h + wo, DM, lin_b + l * DM, yb, DM, ROWS, DM, DM);
        ln_kernel<<<ROWS, 256, 0, stream>>>(xf, yb, n2_s + l * DM, n2_b + l * DM, xf, xb);
    }
    // unembed: [2048,768] x [50257,768]^T -> d_out fp32
    gemm_bt<0><<<dim3(ROWS / 64, (VOCAB + 63) / 64), 256, 0, stream>>>(
        xb, DM, ue_h, DM, unemb_b, (float*)d_out, VOCAB, ROWS, VOCAB, DM);
}

// Round 2
// 809.296 us; speedup vs baseline: 1.0928x; 1.0928x over previous
//
#include <hip/hip_runtime.h>
#include <hip/hip_bf16.h>

// ---------------------------------------------------------------------------
// BYOGPT forward: embed+PE -> 4x[QKV proj, flash-attn, LN, lin, LN] -> unembed
// B=2 S=1024 D=768 H=12 Dh=64 V=50257. bf16 MFMA GEMMs, fp32 residual/LN.
// R2: 128x128-tile GEMM w/ global_load_lds(16B) + XOR swizzle + XCD swizzle,
//     QKV fused into one N=2304 GEMM per layer.
// ---------------------------------------------------------------------------

#define VOCAB 50257
#define DM 768
#define NL 4
#define NH 12
#define DH 64
#define SEQ 1024
#define BATCH 2
#define ROWS (BATCH * SEQ)   // 2048
#define QKVN (3 * DM)        // 2304

typedef __attribute__((ext_vector_type(8))) short short8;
typedef __attribute__((ext_vector_type(4))) float f32x4;

__device__ __forceinline__ unsigned short f2bf(float f) {
    union { float f; unsigned u; } v; v.f = f;
    unsigned r = v.u + 0x7FFFu + ((v.u >> 16) & 1u);   // RNE
    return (unsigned short)(r >> 16);
}

#define GLOAD16(gp, lp)                                                        \
    __builtin_amdgcn_global_load_lds(                                          \
        (const __attribute__((address_space(1))) unsigned int*)(gp),           \
        (__attribute__((address_space(3))) unsigned int*)(lp), 16, 0, 0)

// ---------------- fp32 -> bf16 bulk convert ---------------------------------
__global__ __launch_bounds__(256) void cvt_kernel(const float* __restrict__ in,
                                                  unsigned short* __restrict__ out,
                                                  int n4) {
    int i = blockIdx.x * 256 + threadIdx.x;
    if (i < n4) {
        float4 v = ((const float4*)in)[i];
        ushort4 o;
        o.x = f2bf(v.x); o.y = f2bf(v.y); o.z = f2bf(v.z); o.w = f2bf(v.w);
        ((ushort4*)out)[i] = o;
    }
}

// pack wq/wk/wv (fp32) -> per-layer [2304][768] bf16
__global__ __launch_bounds__(256) void cvt_qkv_kernel(const float* __restrict__ wq,
                                                      const float* __restrict__ wk,
                                                      const float* __restrict__ wv,
                                                      unsigned short* __restrict__ dst,
                                                      int n4) {
    int i = blockIdx.x * 256 + threadIdx.x;
    if (i >= n4) return;
    const int PER_L = 3 * DM * DM / 4, PER_W = DM * DM / 4;
    int l = i / PER_L;
    int rem = i - l * PER_L;
    int w = rem / PER_W;
    int r2 = rem - w * PER_W;
    const float* src = (w == 0) ? wq : (w == 1) ? wk : wv;
    float4 v = ((const float4*)src)[(size_t)l * PER_W + r2];
    ushort4 o;
    o.x = f2bf(v.x); o.y = f2bf(v.y); o.z = f2bf(v.z); o.w = f2bf(v.w);
    ((ushort4*)dst)[i] = o;
}

__global__ __launch_bounds__(256) void pack_qkv_bias(const float* __restrict__ bq,
                                                     const float* __restrict__ bk,
                                                     const float* __restrict__ bv,
                                                     float* __restrict__ dst) {
    int i = blockIdx.x * 256 + threadIdx.x;   // NL*2304
    if (i >= NL * QKVN) return;
    int l = i / QKVN, c = i - l * QKVN;
    int w = c / DM, cc = c - w * DM;
    const float* src = (w == 0) ? bq : (w == 1) ? bk : bv;
    dst[i] = src[l * DM + cc];
}

// ---------------- embedding + positional encoding --------------------------
__global__ __launch_bounds__(256) void embed_kernel(const int* __restrict__ tok,
                                                    const float* __restrict__ emb,
                                                    const float* __restrict__ pe,
                                                    float* __restrict__ xf,
                                                    unsigned short* __restrict__ xb) {
    int row = blockIdx.x;                 // 0..2047
    int t = tok[row];
    int s = row & (SEQ - 1);
    #pragma unroll
    for (int j = 0; j < 3; ++j) {
        int c = threadIdx.x + j * 256;
        float v = emb[(size_t)t * DM + c] + pe[(size_t)s * DM + c];
        xf[(size_t)row * DM + c] = v;
        xb[(size_t)row * DM + c] = f2bf(v);
    }
}

// ---------------- residual + LayerNorm (writes fp32 + bf16) ----------------
__device__ __forceinline__ float block_sum(float x, float* red) {
    #pragma unroll
    for (int off = 32; off > 0; off >>= 1) x += __shfl_down(x, off);
    int w = threadIdx.x >> 6;
    if ((threadIdx.x & 63) == 0) red[w] = x;
    __syncthreads();
    float t = (red[0] + red[1]) + (red[2] + red[3]);
    __syncthreads();
    return t;
}

__global__ __launch_bounds__(256) void ln_kernel(const float* __restrict__ A,
                                                 const float* __restrict__ Bi,
                                                 const float* __restrict__ sc,
                                                 const float* __restrict__ bi,
                                                 float* __restrict__ xf,
                                                 unsigned short* __restrict__ xb) {
    __shared__ float red[4];
    int row = blockIdx.x, tid = threadIdx.x;
    const float* ap = A + (size_t)row * DM;
    const float* bp = Bi + (size_t)row * DM;
    float v[3], sum = 0.f;
    #pragma unroll
    for (int j = 0; j < 3; ++j) { v[j] = ap[tid + j * 256] + bp[tid + j * 256]; sum += v[j]; }
    sum = block_sum(sum, red);
    float mean = sum * (1.f / DM);
    float vs = 0.f;
    #pragma unroll
    for (int j = 0; j < 3; ++j) { float d = v[j] - mean; vs += d * d; }
    vs = block_sum(vs, red);
    float rstd = rsqrtf(vs * (1.f / DM) + 1e-5f);
    #pragma unroll
    for (int j = 0; j < 3; ++j) {
        int c = tid + j * 256;
        float o = (v[j] - mean) * rstd * sc[c] + bi[c];
        xf[(size_t)row * DM + c] = o;
        xb[(size_t)row * DM + c] = f2bf(o);
    }
}

// ---------------- 128x128-tile bf16 GEMM: C[M,N] = A[M,K]*B[N,K]^T + bias --
// 4 waves, each 64x64 (acc[4][4] of 16x16x32 MFMA). global_load_lds 16B
// staging with linear LDS dest + inverse-swizzled global source; XOR-swizzled
// ds_read_b128 (rule #21). XCD-chunked blockIdx swizzle (bijective, nwg%8==0).
template <int OUT_BF16>
__global__ __launch_bounds__(256) void gemm128(const unsigned short* __restrict__ A,
                                               const unsigned short* __restrict__ B,
                                               const float* __restrict__ bias,
                                               void* __restrict__ C,
                                               int M, int N, int K, int gx) {
    __shared__ __align__(16) unsigned short As[128 * 64];
    __shared__ __align__(16) unsigned short Bs[128 * 64];
    int bid = blockIdx.x;
    const int nwg = gridDim.x;
    if ((nwg & 7) == 0) {                       // chunked XCD swizzle
        int q = nwg >> 3;
        bid = (bid & 7) * q + (bid >> 3);
    }
    const int bx = bid % gx, by = bid / gx;
    const int m0 = bx * 128, n0 = by * 128;
    const int tid = threadIdx.x, lane = tid & 63, wid = tid >> 6;
    const int wm = wid >> 1, wn = wid & 1;      // wave -> 64x64 quadrant
    const int lr = lane & 15, lq = lane >> 4;

    // ---- staging geometry: per wave 4 issues of 1KB (8 rows x 128B) -------
    const int sr = wid * 32 + (lane >> 3);      // base LDS row (tile-local)
    const int sch = lane & 7;                   // LDS 16B-chunk within row
    const int scs = sch ^ (sr & 7);             // inverse-swizzled SOURCE chunk
    const unsigned short* aP[4];
    const unsigned short* bP[4];
    unsigned short* aL[4];
    unsigned short* bL[4];
    #pragma unroll
    for (int i = 0; i < 4; ++i) {
        int r = sr + i * 8;                     // (r&7)==(sr&7): scs constant
        aP[i] = A + (size_t)(m0 + r) * K + scs * 8;
        int br = n0 + r; if (br >= N) br = N - 1;   // ragged vocab edge
        bP[i] = B + (size_t)br * K + scs * 8;
        aL[i] = &As[r * 64 + sch * 8];
        bL[i] = &Bs[r * 64 + sch * 8];
    }

    f32x4 acc[4][4] = {};

    for (int k0 = 0; k0 < K; k0 += 64) {
        #pragma unroll
        for (int i = 0; i < 4; ++i) GLOAD16(aP[i] + k0, aL[i]);
        #pragma unroll
        for (int i = 0; i < 4; ++i) GLOAD16(bP[i] + k0, bL[i]);
        __syncthreads();                        // drains vmcnt before compute
        #pragma unroll
        for (int kk = 0; kk < 2; ++kk) {
            short8 a[4], b[4];
            #pragma unroll
            for (int i = 0; i < 4; ++i) {
                int ar = wm * 64 + i * 16 + lr;
                a[i] = *reinterpret_cast<const short8*>(
                    &As[ar * 64 + (((kk * 4 + lq) ^ (ar & 7)) * 8)]);
                int br = wn * 64 + i * 16 + lr;
                b[i] = *reinterpret_cast<const short8*>(
                    &Bs[br * 64 + (((kk * 4 + lq) ^ (br & 7)) * 8)]);
            }
            #pragma unroll
            for (int i = 0; i < 4; ++i)
                #pragma unroll
                for (int j = 0; j < 4; ++j)
                    acc[i][j] = __builtin_amdgcn_mfma_f32_16x16x32_bf16(a[i], b[j], acc[i][j], 0, 0, 0);
        }
        __syncthreads();
    }
    // epilogue: C/D layout col=lane&15, row=(lane>>4)*4+reg  [m89-verified]
    #pragma unroll
    for (int i = 0; i < 4; ++i) {
        int row = m0 + wm * 64 + i * 16 + lq * 4;
        #pragma unroll
        for (int j = 0; j < 4; ++j) {
            int col = n0 + wn * 64 + j * 16 + lr;
            if (col < N) {
                float bv = bias[col];
                #pragma unroll
                for (int r = 0; r < 4; ++r) {
                    float v = acc[i][j][r] + bv;
                    if (OUT_BF16) ((unsigned short*)C)[(size_t)(row + r) * N + col] = f2bf(v);
                    else          ((float*)C)[(size_t)(row + r) * N + col] = v;
                }
            }
        }
    }
}

// ---------------- flash attention (causal), bf16 MFMA ----------------------
// grid (S/64, B*H); 4 waves, each owns 16 q-rows. KV tiles of 64.
// Q/K/V read from fused qkv buffer with row stride ld.
__global__ __launch_bounds__(256) void attn_kernel(const unsigned short* __restrict__ Q,
                                                   const unsigned short* __restrict__ K,
                                                   const unsigned short* __restrict__ V,
                                                   int ld,
                                                   float* __restrict__ O) {
    __shared__ __align__(16) unsigned short Ks[64 * 64];
    __shared__ __align__(16) unsigned short Vs[64 * 64];     // transposed [d][kv]
    __shared__ __align__(16) unsigned short Ps[4][16 * 64];  // per-wave P tile
    const int qb = blockIdx.x;
    const int bh = blockIdx.y;
    const int b = bh / NH, h = bh % NH;
    const int tid = threadIdx.x, lane = tid & 63, w = tid >> 6;
    const int lr = lane & 15, lq = lane >> 4;
    const int wq0 = qb * 64 + w * 16;
    const size_t base = (size_t)b * SEQ * ld + h * DH;
    const size_t obase = (size_t)b * SEQ * DM + h * DH;

    short8 qf[2];
    {
        const unsigned short* qp = Q + base + (size_t)(wq0 + lr) * ld + lq * 8;
        qf[0] = *reinterpret_cast<const short8*>(qp);
        qf[1] = *reinterpret_cast<const short8*>(qp + 32);
    }
    f32x4 o_acc[4] = {};
    float mrow[4], lrow[4];
    #pragma unroll
    for (int r = 0; r < 4; ++r) { mrow[r] = -1e30f; lrow[r] = 0.f; }

    const int srow = tid >> 3, scol = (tid & 7) * 8;
    for (int t = 0; t <= qb; ++t) {
        const int kv0 = t * 64;
        #pragma unroll
        for (int rr = 0; rr < 2; ++rr) {
            int row = rr * 32 + srow;
            {
                const unsigned short* kp = K + base + (size_t)(kv0 + row) * ld + scol;
                short8 v = *reinterpret_cast<const short8*>(kp);
                *reinterpret_cast<short8*>(&Ks[(row * 64 + scol) ^ ((row & 7) << 3)]) = v;
            }
            {
                const unsigned short* vp = V + base + (size_t)(kv0 + row) * ld + scol;
                short8 v = *reinterpret_cast<const short8*>(vp);
                #pragma unroll
                for (int j = 0; j < 8; ++j) {   // transpose into Vs[d][kv]
                    int d = scol + j;
                    Vs[(d * 64 + row) ^ ((d & 7) << 3)] = (unsigned short)v[j];
                }
            }
        }
        __syncthreads();
        if (kv0 <= wq0 + 15) {
            f32x4 s[4];
            #pragma unroll
            for (int n = 0; n < 4; ++n) {
                int br = n * 16 + lr;
                short8 b0 = *reinterpret_cast<const short8*>(&Ks[(br * 64 + lq * 8) ^ ((br & 7) << 3)]);
                short8 b1 = *reinterpret_cast<const short8*>(&Ks[(br * 64 + 32 + lq * 8) ^ ((br & 7) << 3)]);
                f32x4 z = {};
                z = __builtin_amdgcn_mfma_f32_16x16x32_bf16(qf[0], b0, z, 0, 0, 0);
                z = __builtin_amdgcn_mfma_f32_16x16x32_bf16(qf[1], b1, z, 0, 0, 0);
                s[n] = z;
            }
            const bool diag = (t == qb);
            #pragma unroll
            for (int n = 0; n < 4; ++n)
                #pragma unroll
                for (int r = 0; r < 4; ++r) {
                    float v = s[n][r] * 0.125f;   // 1/sqrt(64)
                    if (diag) {
                        int rg = wq0 + lq * 4 + r;
                        int cg = kv0 + n * 16 + lr;
                        if (cg > rg) v = -1e30f;
                    }
                    s[n][r] = v;
                }
            float f[4];
            #pragma unroll
            for (int r = 0; r < 4; ++r) {
                float mx = fmaxf(fmaxf(s[0][r], s[1][r]), fmaxf(s[2][r], s[3][r]));
                #pragma unroll
                for (int off = 1; off < 16; off <<= 1) mx = fmaxf(mx, __shfl_xor(mx, off));
                float mn = fmaxf(mrow[r], mx);
                f[r] = exp2f((mrow[r] - mn) * 1.44269504f);
                mrow[r] = mn;
            }
            #pragma unroll
            for (int n = 0; n < 4; ++n)
                #pragma unroll
                for (int r = 0; r < 4; ++r)
                    s[n][r] = exp2f((s[n][r] - mrow[r]) * 1.44269504f);
            #pragma unroll
            for (int r = 0; r < 4; ++r) {
                float ls = ((s[0][r] + s[1][r]) + (s[2][r] + s[3][r]));
                #pragma unroll
                for (int off = 1; off < 16; off <<= 1) ls += __shfl_xor(ls, off);
                lrow[r] = lrow[r] * f[r] + ls;
            }
            #pragma unroll
            for (int n = 0; n < 4; ++n)
                #pragma unroll
                for (int r = 0; r < 4; ++r) {
                    int pr = lq * 4 + r, pc = n * 16 + lr;
                    Ps[w][(pr * 64 + pc) ^ ((pr & 7) << 3)] = f2bf(s[n][r]);
                }
            #pragma unroll
            for (int n = 0; n < 4; ++n)
                #pragma unroll
                for (int r = 0; r < 4; ++r) o_acc[n][r] *= f[r];
            #pragma unroll
            for (int kk = 0; kk < 2; ++kk) {
                short8 pa = *reinterpret_cast<const short8*>(
                    &Ps[w][(lr * 64 + kk * 32 + lq * 8) ^ ((lr & 7) << 3)]);
                #pragma unroll
                for (int n = 0; n < 4; ++n) {
                    int vr = n * 16 + lr;
                    short8 bv = *reinterpret_cast<const short8*>(
                        &Vs[(vr * 64 + kk * 32 + lq * 8) ^ ((vr & 7) << 3)]);
                    o_acc[n] = __builtin_amdgcn_mfma_f32_16x16x32_bf16(pa, bv, o_acc[n], 0, 0, 0);
                }
            }
        }
        __syncthreads();
    }
    #pragma unroll
    for (int r = 0; r < 4; ++r) {
        float inv = 1.f / lrow[r];
        int row = wq0 + lq * 4 + r;
        #pragma unroll
        for (int n = 0; n < 4; ++n)
            O[obase + (size_t)row * DM + n * 16 + lr] = o_acc[n][r] * inv;
    }
}

// ---------------------------------------------------------------------------
extern "C" void kernel_launch(void* const* d_in, const int* in_sizes, int n_in,
                              void* d_out, int out_size, void* d_ws, size_t ws_size,
                              hipStream_t stream) {
    const int*   tokens   = (const int*)d_in[0];
    const float* embed    = (const float*)d_in[1];
    const float* pe       = (const float*)d_in[2];
    const float* wq_w     = (const float*)d_in[3];
    const float* wq_b     = (const float*)d_in[4];
    const float* wk_w     = (const float*)d_in[5];
    const float* wk_b     = (const float*)d_in[6];
    const float* wv_w     = (const float*)d_in[7];
    const float* wv_b     = (const float*)d_in[8];
    const float* lin_w    = (const float*)d_in[9];
    const float* lin_b    = (const float*)d_in[10];
    const float* n1_s     = (const float*)d_in[11];
    const float* n1_b     = (const float*)d_in[12];
    const float* n2_s     = (const float*)d_in[13];
    const float* n2_b     = (const float*)d_in[14];
    const float* unemb_w  = (const float*)d_in[15];
    const float* unemb_b  = (const float*)d_in[16];

    char* ws = (char*)d_ws;
    size_t off = 0;
    auto carve = [&](size_t bytes) { char* p = ws + off; off += (bytes + 255) & ~(size_t)255; return p; };
    float*          xf     = (float*)carve((size_t)ROWS * DM * 4);
    float*          yb     = (float*)carve((size_t)ROWS * DM * 4);   // attn-out & lin-out
    unsigned short* xb     = (unsigned short*)carve((size_t)ROWS * DM * 2);
    unsigned short* qkv    = (unsigned short*)carve((size_t)ROWS * QKVN * 2);
    unsigned short* wqkv_h = (unsigned short*)carve((size_t)NL * QKVN * DM * 2);
    unsigned short* lin_h  = (unsigned short*)carve((size_t)NL * DM * DM * 2);
    unsigned short* ue_h   = (unsigned short*)carve((size_t)VOCAB * DM * 2);
    float*          qkvb   = (float*)carve((size_t)NL * QKVN * 4);

    // weight converts / packs (fp32 -> bf16)
    {
        int nq4 = NL * QKVN * DM / 4;
        cvt_qkv_kernel<<<(nq4 + 255) / 256, 256, 0, stream>>>(wq_w, wk_w, wv_w, wqkv_h, nq4);
        int nl4 = NL * DM * DM / 4;
        cvt_kernel<<<(nl4 + 255) / 256, 256, 0, stream>>>(lin_w, lin_h, nl4);
        int nu4 = VOCAB * DM / 4;
        cvt_kernel<<<(nu4 + 255) / 256, 256, 0, stream>>>(unemb_w, ue_h, nu4);
        pack_qkv_bias<<<(NL * QKVN + 255) / 256, 256, 0, stream>>>(wq_b, wk_b, wv_b, qkvb);
    }
    embed_kernel<<<ROWS, 256, 0, stream>>>(tokens, embed, pe, xf, xb);

    const int gx = ROWS / 128;   // 16 M-blocks
    for (int l = 0; l < NL; ++l) {
        // fused QKV: [2048,768] x [2304,768]^T -> qkv [2048,2304] bf16
        gemm128<1><<<gx * (QKVN / 128), 256, 0, stream>>>(
            xb, wqkv_h + (size_t)l * QKVN * DM, qkvb + l * QKVN, qkv,
            ROWS, QKVN, DM, gx);
        attn_kernel<<<dim3(SEQ / 64, BATCH * NH), 256, 0, stream>>>(
            qkv, qkv + DM, qkv + 2 * DM, QKVN, yb);
        ln_kernel<<<ROWS, 256, 0, stream>>>(xf, yb, n1_s + l * DM, n1_b + l * DM, xf, xb);
        gemm128<0><<<gx * (DM / 128), 256, 0, stream>>>(
            xb, lin_h + (size_t)l * DM * DM, lin_b + l * DM, yb,
            ROWS, DM, DM, gx);
        ln_kernel<<<ROWS, 256, 0, stream>>>(xf, yb, n2_s + l * DM, n2_b + l * DM, xf, xb);
    }
    // unembed: [2048,768] x [50257,768]^T -> d_out fp32 [2048,50257]
    const int gyu = (VOCAB + 127) / 128;   // 393
    gemm128<0><<<gx * gyu, 256, 0, stream>>>(
        xb, ue_h, unemb_b, (float*)d_out, ROWS, VOCAB, DM, gx);
}